// Round 8
// baseline (240.808 us; speedup 1.0000x reference)
//
#include <hip/hip_runtime.h>

// TokenEmbedding segment-sum, MI355X. v8: pipelined slice streaming.
//
// Evidence so far: block-per-token 72us; wave-per-token 86; block-per-8tok
// 85; dependence-free slice gather (v7) 84us at 2.4 TB/s with VALUBusy 1.7%.
// The harness fill reaches 6.8 TB/s at NINE percent occupancy -> the memory
// system wants CONTINUOUS per-wave outstanding traffic, not more waves.
// All previous variants were burst-drain-die (one load burst per wave
// lifetime, pipeline drains at every block retire).
//
// v8: one 256-thread block per 32 consecutive input rows (1024 blocks).
// Rows processed as 4 slices of 8 with an A/B register double-buffer:
// while slice k is walked (v7's proven segmentation logic, state carried
// across slices), slice k+1's 8 row loads + token s_loads are in flight.
// Load addresses remain pure functions of blockIdx/threadIdx. Each wave
// keeps ~8 KB of reads outstanding for its entire lifetime.
//
// Ownership (exactly-once writes, poison-safe, no atomics, no workspace):
//   - a block owns token t iff t's run STARTS in its row range;
//   - runs crossing the block end are finished with dynamic loads
//     (run lengths ~Poisson(1), extension ~1 row expected);
//   - empty tokens are zero-stored by the block containing their
//     insertion row; batch-trailing empties by the batch's last block.

#define B_DIM 8
#define L_DIM 4096
#define RPS 8                   // rows per slice (pipeline unit)
#define NSLICE 4                // slices per block
#define RPB (RPS * NSLICE)      // rows per block = 32
#define BPB (L_DIM / RPB)       // blocks per batch = 128

typedef float fx4 __attribute__((ext_vector_type(4)));

// Load slice starting at row rr into (BUF, TK). Addresses blockIdx-pure.
#define SLICE_LOAD(BUF, TK, rr)                                  \
    {                                                            \
        _Pragma("unroll")                                        \
        for (int r = 0; r < RPS; ++r) {                          \
            BUF[r] = base[(size_t)((rr) + r) << 8];              \
            TK[r]  = trow[(rr) + r];                             \
        }                                                        \
    }

// Walk one slice: v7 logic, state (acc, prev, started) carried.
#define SLICE_WALK(BUF, TK)                                      \
    {                                                            \
        _Pragma("unroll")                                        \
        for (int r = 0; r < RPS; ++r) {                          \
            const int t = TK[r];                                 \
            if (t != prev) {                                     \
                if (started)                                     \
                    __builtin_nontemporal_store(                 \
                        acc, obase + ((size_t)prev << 8));       \
                for (int j = prev + 1; j < t; ++j)               \
                    __builtin_nontemporal_store(                 \
                        (fx4)0.f, obase + ((size_t)j << 8));     \
                acc = BUF[r];                                    \
                prev = t;                                        \
                started = true;                                  \
            } else if (started) {                                \
                acc += BUF[r];                                   \
            }                                                    \
        }                                                        \
    }

__global__ __launch_bounds__(256) void token_seg_sum_kernel(
    const float* __restrict__ seq,   // [B, L, H] fp32
    const int* __restrict__ tok,     // [B, L] sorted per batch
    float* __restrict__ out)         // [B, L, H] fp32
{
    const int g  = blockIdx.x;            // 0 .. B*BPB-1
    const int b  = g / BPB;
    const int r0 = (g % BPB) * RPB;       // first input row of this block

    const int tid = threadIdx.x;          // one fx4 column slot per thread
    const fx4* __restrict__ base = (const fx4*)seq + ((size_t)b << 20) + tid;
    fx4* __restrict__ obase      = (fx4*)out + ((size_t)b << 20) + tid;
    const int* __restrict__ trow = tok + ((size_t)b << 12);

    fx4 bufA[RPS], bufB[RPS];
    int tkA[RPS], tkB[RPS];

    // Prologue: slice 0 in flight.
    SLICE_LOAD(bufA, tkA, r0)

    fx4 acc = (fx4)0.f;
    int  prev    = (r0 == 0) ? -1 : trow[r0 - 1];
    bool started = false;

    // Steady state: prefetch k+1 while walking k. NSLICE even -> A/B pairs.
#pragma unroll
    for (int sp = 0; sp < NSLICE; sp += 2) {
        SLICE_LOAD(bufB, tkB, r0 + (sp + 1) * RPS)   // prefetch sp+1
        SLICE_WALK(bufA, tkA)                        // walk sp
        if (sp + 2 < NSLICE)
            SLICE_LOAD(bufA, tkA, r0 + (sp + 2) * RPS)  // prefetch sp+2
        SLICE_WALK(bufB, tkB)                        // walk sp+1
    }

    // Tail: finish the run crossing the block end (rare, ~1 row expected).
    if (started) {
        int w = r0 + RPB;
        while (w < L_DIM && trow[w] == prev) {
            acc += base[(size_t)w << 8];
            ++w;
        }
        __builtin_nontemporal_store(acc, obase + ((size_t)prev << 8));
    }

    // Batch's last block also owns trailing empty tokens.
    if (r0 + RPB == L_DIM) {
        const int tlast = trow[L_DIM - 1];
        for (int j = tlast + 1; j < L_DIM; ++j)
            __builtin_nontemporal_store((fx4)0.f, obase + ((size_t)j << 8));
    }
}

extern "C" void kernel_launch(void* const* d_in, const int* in_sizes, int n_in,
                              void* d_out, int out_size, void* d_ws, size_t ws_size,
                              hipStream_t stream) {
    const float* seq = (const float*)d_in[0];
    const int*   tok = (const int*)d_in[1];
    float*       out = (float*)d_out;
    (void)d_ws; (void)ws_size;

    // One block per 32-row input slice group: B*L/RPB = 1024 blocks.
    token_seg_sum_kernel<<<dim3(B_DIM * BPB), dim3(256), 0, stream>>>(
        seq, tok, out);
}